// Round 7
// baseline (213.893 us; speedup 1.0000x reference)
//
#include <hip/hip_runtime.h>
#include <math.h>

// fp16-MFMA fused MHA-like layer (fp32 accumulate), round 11:
//  - R11: mid load-balance fix. 528 equal tiles on 256 CUs = 16 CUs with 3
//    blocks vs 240 with 2 -> makespan 1.46x balanced (mid ran 417 TF vs
//    qkv's 645 with identical gemm_acc). Now: persistent grid 512 (2/CU)
//    popping tiles from an atomic queue (counter in ws, zeroed by prep).
//    Balances to +-1 tile regardless of CU assignment.
//  - R10: softmax traffic trim (load j<=i, store j<kend only).
//  - gemm_acc: double-buffered LDS, ONE barrier per K-step, BK=32.
//  - Swizzle: stage src chunk (l&3)^((l>>3)&3), read slot quad^((row>>1)&3).
//  - 5 dispatches: prep, QKV, mid (QK^T || V@Wo), softmax, PV->out

typedef _Float16 f16x8 __attribute__((ext_vector_type(8)));
typedef float f32x4 __attribute__((ext_vector_type(4)));

#define BK 32   // halves per LDS row (64 B)

__device__ __forceinline__ void gload_lds16(const void* g, void* l) {
  __builtin_amdgcn_global_load_lds(
      (const __attribute__((address_space(1))) void*)g,
      (__attribute__((address_space(3))) void*)l, 16, 0, 0);
}

// Accumulate C-tile (m0,n0) of A[*,sAr] @ BT[*,sBr]^T over k < kend.
// Ah/Bh are double buffers: 2 * TMp*BK / 2 * TNp*BK halves.
// LDS: [row][chunk] chunks of 8 halves (16B); logical chunk c of row r at
// physical slot c ^ ((r>>1)&3). Staging swizzles the global source side
// (global_load_lds LDS dest must stay lane-linear); ds_read mirrors it.
template<int TMp, int TNp>
__device__ __forceinline__ void gemm_acc(
    const _Float16* __restrict__ A, const _Float16* __restrict__ BT,
    _Float16* Ah, _Float16* Bh, int sAr, int sBr, int kend, int m0, int n0,
    f32x4 (&acc)[TMp / 32][TNp / 32])
{
  const int tid  = threadIdx.x;
  const int lane = tid & 63;
  const int wid  = tid >> 6;
  const int wm   = (wid >> 1) * (TMp / 2);
  const int wn   = (wid & 1) * (TNp / 2);
  const int l15  = lane & 15;
  const int quad = lane >> 4;
  constexpr int MT = TMp / 32;
  constexpr int NT = TNp / 32;
  constexpr int AI = TMp / 64;            // staging instrs per wave (16 rows)
  constexpr int BI = TNp / 64;
  const int r16 = lane >> 2;              // row within 16-row group
  const int swc = ((lane & 3) ^ ((lane >> 3) & 3)) * 8;  // swizzled src chunk
  const int arow = wid * (TMp / 4);
  const int brow = wid * (TNp / 4);

  auto stage = [&](int k0, int buf) {
    _Float16* Ad = Ah + buf * (TMp * BK);
    _Float16* Bd = Bh + buf * (TNp * BK);
    #pragma unroll
    for (int t = 0; t < AI; ++t)
      gload_lds16(A + (long long)(m0 + arow + t * 16 + r16) * sAr + k0 + swc,
                  Ad + (arow + t * 16) * BK);
    #pragma unroll
    for (int t = 0; t < BI; ++t)
      gload_lds16(BT + (long long)(n0 + brow + t * 16 + r16) * sBr + k0 + swc,
                  Bd + (brow + t * 16) * BK);
  };

  stage(0, 0);
  __syncthreads();                        // drain vmcnt(0) for step 0
  int cur = 0;
  for (int k0 = 0; k0 < kend; k0 += BK) {
    if (k0 + BK < kend) stage(k0 + BK, cur ^ 1);   // prefetch next step

    const int ch = (quad ^ ((l15 >> 1) & 3)) * 8;  // swizzled read slot
    const _Float16* ab = Ah + cur * (TMp * BK) + (wm + l15) * BK + ch;
    const _Float16* bb = Bh + cur * (TNp * BK) + (wn + l15) * BK + ch;
    f16x8 af[MT], bf[NT];
    #pragma unroll
    for (int t = 0; t < MT; ++t) af[t] = *(const f16x8*)(ab + t * 16 * BK);
    #pragma unroll
    for (int t = 0; t < NT; ++t) bf[t] = *(const f16x8*)(bb + t * 16 * BK);
    #pragma unroll
    for (int mt = 0; mt < MT; ++mt)
      #pragma unroll
      for (int nt = 0; nt < NT; ++nt)
        acc[mt][nt] = __builtin_amdgcn_mfma_f32_16x16x32_f16(
            af[mt], bf[nt], acc[mt][nt], 0, 0, 0);

    __syncthreads();   // one barrier/step: drains prefetch vmcnt + syncs reads
    cur ^= 1;
  }
}

// Epilogue. C/D layout: col = lane&15, row = quad*4 + reg (HW-verified).
template<int TMp, int TNp, bool RELU, bool HAS_BIAS, typename OT>
__device__ __forceinline__ void gemm_store(
    f32x4 (&acc)[TMp / 32][TNp / 32], const float* __restrict__ bias,
    OT* __restrict__ C, int Nout, float scale, int m0, int n0)
{
  const int tid  = threadIdx.x;
  const int lane = tid & 63;
  const int wid  = tid >> 6;
  const int wm   = (wid >> 1) * (TMp / 2);
  const int wn   = (wid & 1) * (TNp / 2);
  const int l15  = lane & 15;
  const int quad = lane >> 4;
  constexpr int MT = TMp / 32;
  constexpr int NT = TNp / 32;

  float bvals[NT];
  if (HAS_BIAS) {
    #pragma unroll
    for (int nt = 0; nt < NT; ++nt)
      bvals[nt] = bias[n0 + wn + nt * 16 + l15];
  }
  #pragma unroll
  for (int mt = 0; mt < MT; ++mt) {
    #pragma unroll
    for (int nt = 0; nt < NT; ++nt) {
      const int col = n0 + wn + nt * 16 + l15;
      #pragma unroll
      for (int r = 0; r < 4; ++r) {
        const int row = m0 + wm + mt * 16 + quad * 4 + r;
        float v = acc[mt][nt][r] * scale;
        if (HAS_BIAS) v += bvals[nt];
        if (RELU) v = fmaxf(v, 0.f);
        C[(long long)row * Nout + col] = (OT)v;
      }
    }
  }
}

// fused QKV: relu(x @ W{q,k,v} + b) -> f16; Wcat = [Wq^T;Wk^T;Wv^T;Wo^T]
__global__ __launch_bounds__(256) void qkv_kernel(
    const _Float16* __restrict__ xh, const _Float16* __restrict__ Wcat,
    const float* __restrict__ bq, const float* __restrict__ bk,
    const float* __restrict__ bv,
    _Float16* __restrict__ Qh, _Float16* __restrict__ Kh,
    _Float16* __restrict__ Vh, int D)
{
  __shared__ _Float16 Ah[2 * 128 * BK];
  __shared__ _Float16 Bh[2 * 128 * BK];
  const int m0  = blockIdx.y * 128;
  const int n0g = blockIdx.x * 128;       // 0..3071
  f32x4 acc[4][4];
  #pragma unroll
  for (int i = 0; i < 4; ++i)
    #pragma unroll
    for (int j = 0; j < 4; ++j) acc[i][j] = (f32x4){0.f, 0.f, 0.f, 0.f};

  gemm_acc<128, 128>(xh, Wcat, Ah, Bh, D, D, D, m0, n0g, acc);

  const int mat = n0g >> 10;              // D = 1024
  const int c0  = n0g & 1023;
  _Float16* C = (mat == 0) ? Qh : (mat == 1) ? Kh : Vh;
  const float* bias = (mat == 0) ? bq : (mat == 1) ? bk : bv;
  gemm_store<128, 128, true, true, _Float16>(acc, bias, C, D, 1.0f, m0, c0);
}

// mid: tiles 0..271 -> E = QK^T/32 (packed triangular, 128x128);
//      tiles 272..527 -> VWT = (V@Wo)^T (A = Wo^T, BT = V), 128x128.
// Persistent grid 512 (2 blocks/CU), tiles popped from atomic queue ->
// work balances to +-1 tile across CUs (528 static tiles gave 16 CUs a
// 3rd block = 1.46x makespan). Counter zeroed by prep (stream order).
// Diagonal QK^T tiles compute a garbage upper half; softmax zeroes the
// region pv reads (j < kend) and pv never reads past kend.
__global__ __launch_bounds__(256) void mid_kernel(
    const _Float16* __restrict__ Qh, const _Float16* __restrict__ Kh,
    _Float16* __restrict__ E, const _Float16* __restrict__ WoT,
    const _Float16* __restrict__ Vh, _Float16* __restrict__ VWT,
    int S, int D, int* __restrict__ cnt)
{
  __shared__ _Float16 Ah[2 * 128 * BK];
  __shared__ _Float16 Bh[2 * 128 * BK];
  __shared__ int s_id;
  for (;;) {
    if (threadIdx.x == 0) s_id = atomicAdd(cnt, 1);
    __syncthreads();
    const int id = s_id;
    if (id >= 528) return;

    const _Float16 *A, *BT;
    _Float16* C;
    int m0, n0;
    float scale;
    if (id < 272) {                        // QK^T, 136 tiles per batch
      const int z = (id >= 136);
      const int t = id - z * 136;
      int i = (int)((sqrtf(8.f * t + 1.f) - 1.f) * 0.5f);
      while ((i + 1) * (i + 2) / 2 <= t) ++i;
      while (i * (i + 1) / 2 > t) --i;
      const int j = t - i * (i + 1) / 2;   // 0..i
      m0 = i * 128;
      n0 = j * 128;
      A  = Qh + (long long)z * S * D;
      BT = Kh + (long long)z * S * D;
      C  = E + (long long)z * S * S;
      scale = 0.03125f;
    } else {                               // V @ Wo, 128 tiles per batch
      const int t = id - 272;
      const int z = t >> 7;
      const int u = t & 127;
      m0 = (u >> 4) * 128;                 // D rows of Wo^T
      n0 = (u & 15) * 128;                 // S cols (V rows)
      A  = WoT;
      BT = Vh + (long long)z * S * D;
      C  = VWT + (long long)z * D * S;
      scale = 1.0f;
    }
    f32x4 acc[4][4];
    #pragma unroll
    for (int i = 0; i < 4; ++i)
      #pragma unroll
      for (int j = 0; j < 4; ++j) acc[i][j] = (f32x4){0.f, 0.f, 0.f, 0.f};

    gemm_acc<128, 128>(A, BT, Ah, Bh, D, D, D, m0, n0, acc);
    gemm_store<128, 128, false, false, _Float16>(acc, nullptr, C, S, scale,
                                                 m0, n0);
    // gemm_acc's final __syncthreads closed all LDS reads; store touches
    // only regs/global, so the next iteration's stage() may overlap it.
  }
}

// out = relu(P @ VW + bo) -> fp32; kend = m0+64 (causal cap); heavy tiles first
__global__ __launch_bounds__(256) void pv_kernel(
    const _Float16* __restrict__ E, const _Float16* __restrict__ VWT,
    const float* __restrict__ bo, float* __restrict__ out, int S, int D)
{
  __shared__ _Float16 Ah[2 * 64 * BK];
  __shared__ _Float16 Bh[2 * 128 * BK];
  const int z  = blockIdx.z;
  const int m0 = ((int)gridDim.y - 1 - (int)blockIdx.y) * 64;
  const int n0 = blockIdx.x * 128;
  const _Float16* A  = E + (long long)z * S * S;
  const _Float16* BT = VWT + (long long)z * D * S;
  float* C = out + (long long)z * S * D;
  const int kend = m0 + 64;

  f32x4 acc[2][4];
  #pragma unroll
  for (int i = 0; i < 2; ++i)
    #pragma unroll
    for (int j = 0; j < 4; ++j) acc[i][j] = (f32x4){0.f, 0.f, 0.f, 0.f};

  gemm_acc<64, 128>(A, BT, Ah, Bh, S, S, kend, m0, n0, acc);
  gemm_store<64, 128, true, true, float>(acc, bo, C, D, 1.0f, m0, n0);
}

// prep: blocks 0..2047 = x fp32->f16 (8 elems/thread);
//       blocks 2048..3071 = W transpose+convert into Wcat (64x64 tiles, z=mat)
// Block 0 thread 0 also zeroes the mid work-queue counter.
__global__ __launch_bounds__(256) void prep_kernel(
    const float* __restrict__ x, _Float16* __restrict__ xh,
    const float* __restrict__ W0, const float* __restrict__ W1,
    const float* __restrict__ W2, const float* __restrict__ W3,
    _Float16* __restrict__ Wcat, int D, int* __restrict__ cnt)
{
  const int id = blockIdx.x;
  const int tid = threadIdx.x;
  if (id == 0 && tid == 0) *cnt = 0;
  if (id < 2048) {
    const long long i = ((long long)id * 256 + tid) * 8;
    float4 a = *(const float4*)(x + i);
    float4 b = *(const float4*)(x + i + 4);
    f16x8 o = {(_Float16)a.x, (_Float16)a.y, (_Float16)a.z, (_Float16)a.w,
               (_Float16)b.x, (_Float16)b.y, (_Float16)b.z, (_Float16)b.w};
    *(f16x8*)(xh + i) = o;
    return;
  }
  __shared__ _Float16 t[64][72];
  const int u = id - 2048;
  const int z = u >> 8;
  const int v = u & 255;
  const float* W = (z == 0) ? W0 : (z == 1) ? W1 : (z == 2) ? W2 : W3;
  _Float16* dst = Wcat + (long long)z * D * D;
  const int k0 = (v >> 4) * 64, n0 = (v & 15) * 64;
  #pragma unroll
  for (int it = 0; it < 4; ++it) {
    int idx = tid + it * 256;
    int r = idx >> 4, c4 = (idx & 15) << 2;
    float4 w = *(const float4*)(W + (long long)(k0 + r) * D + n0 + c4);
    t[r][c4 + 0] = (_Float16)w.x; t[r][c4 + 1] = (_Float16)w.y;
    t[r][c4 + 2] = (_Float16)w.z; t[r][c4 + 3] = (_Float16)w.w;
  }
  __syncthreads();
  #pragma unroll
  for (int it = 0; it < 2; ++it) {
    int idx = tid + it * 256;
    int r = idx >> 3, c8 = (idx & 7) << 3;
    f16x8 o;
    #pragma unroll
    for (int j = 0; j < 8; ++j) o[j] = t[c8 + j][r];
    *(f16x8*)(dst + (long long)(n0 + r) * D + k0 + c8) = o;
  }
}

// in-place causal softmax, fp32 math, f16 IO; zeros for j > i.
// Load only j0 < n (rest contribute -inf/0 to the reductions);
// store only j0 < kend=(i&~63)+64 -- pv's K-loop never reads past kend,
// so raw mid garbage may remain at j >= kend. No early returns: every
// thread reaches both __syncthreads.
__global__ __launch_bounds__(256) void softmax_causal_h(
    _Float16* __restrict__ E, int S)
{
  const int i = blockIdx.x;
  _Float16* row = E + ((long long)blockIdx.y * S + i) * S;
  const int tid = threadIdx.x;
  const int n = i + 1;
  const int kend = (i & ~63) + 64;
  const int j0 = tid * 8;

  f16x8 hv;
  const bool has = (j0 < n);
  if (has) hv = *(const f16x8*)(row + j0);
  float vals[8];
  float m = -3.0e38f;
  #pragma unroll
  for (int t = 0; t < 8; ++t) {
    float v = (has && j0 + t < n) ? (float)hv[t] : -3.0e38f;
    vals[t] = v;
    m = fmaxf(m, v);
  }
  #pragma unroll
  for (int o = 32; o > 0; o >>= 1) m = fmaxf(m, __shfl_down(m, o, 64));

  __shared__ float rmax[4];
  __shared__ float rsum[4];
  const int wave = tid >> 6;
  if ((tid & 63) == 0) rmax[wave] = m;
  __syncthreads();
  m = fmaxf(fmaxf(rmax[0], rmax[1]), fmaxf(rmax[2], rmax[3]));

  float s = 0.f;
  #pragma unroll
  for (int t = 0; t < 8; ++t) {
    float e = (has && j0 + t < n) ? expf(vals[t] - m) : 0.f;
    vals[t] = e;
    s += e;
  }
  #pragma unroll
  for (int o = 32; o > 0; o >>= 1) s += __shfl_down(s, o, 64);
  if ((tid & 63) == 0) rsum[wave] = s;
  __syncthreads();
  s = rsum[0] + rsum[1] + rsum[2] + rsum[3];

  if (j0 < kend) {
    const float inv = 1.0f / s;
    f16x8 ov;
    #pragma unroll
    for (int t = 0; t < 8; ++t) ov[t] = (_Float16)(vals[t] * inv);
    *(f16x8*)(row + j0) = ov;
  }
}

extern "C" void kernel_launch(void* const* d_in, const int* in_sizes, int n_in,
                              void* d_out, int out_size, void* d_ws, size_t ws_size,
                              hipStream_t stream) {
  const float* x  = (const float*)d_in[0];
  const float* Wq = (const float*)d_in[1];
  const float* bq = (const float*)d_in[2];
  const float* Wk = (const float*)d_in[3];
  const float* bk = (const float*)d_in[4];
  const float* Wv = (const float*)d_in[5];
  const float* bv = (const float*)d_in[6];
  const float* Wo = (const float*)d_in[7];
  const float* bo = (const float*)d_in[8];
  float* out = (float*)d_out;

  const int Bn = 2, S = 2048, D = 1024;
  const int M = Bn * S;                       // 4096
  const size_t MD = (size_t)M * D;            // 4M elems
  const size_t DD = (size_t)D * D;            // 1M
  const size_t SS = (size_t)Bn * S * S;       // 8M

  _Float16* ws   = (_Float16*)d_ws;
  _Float16* xh   = ws;                 // MD
  _Float16* Wcat = xh + MD;            // 4*DD
  _Float16* Qh   = Wcat + 4 * DD;      // MD
  _Float16* Kh   = Qh + MD;            // MD
  _Float16* Vh   = Kh + MD;            // MD
  _Float16* VWT  = Vh + MD;            // MD  ((V@Wo)^T, [D,S] per batch)
  _Float16* E    = VWT + MD;           // SS
  int* cnt       = (int*)(E + SS);     // mid work-queue counter (4 B)

  dim3 blk(256);

  prep_kernel<<<dim3(3072), blk, 0, stream>>>(x, xh, Wq, Wk, Wv, Wo, Wcat, D,
                                              cnt);

  qkv_kernel<<<dim3(3 * D / 128, M / 128), blk, 0, stream>>>(
      xh, Wcat, bq, bk, bv, Qh, Kh, Vh, D);

  mid_kernel<<<dim3(512), blk, 0, stream>>>(
      Qh, Kh, E, Wcat + 3 * DD, Vh, VWT, S, D, cnt);

  softmax_causal_h<<<dim3(S, Bn), blk, 0, stream>>>(E, S);

  pv_kernel<<<dim3(D / 128, S / 64, Bn), blk, 0, stream>>>(
      E, VWT, bo, out, S, D);
}

// Round 11
// 197.528 us; speedup vs baseline: 1.0829x; 1.0829x over previous
//
#include <hip/hip_runtime.h>
#include <math.h>

// fp16-MFMA fused MHA-like layer (fp32 accumulate), round 13:
//  - R13: mid STATIC mixed-granularity balance (no queue/atomics -- the
//    3x-failed R12 queue source is abandoned per kill-criterion).
//    768 blocks = 3/CU exactly, heavy-first:
//      ids 0..271   QK^T 128x128 (packed triangular, cost 1)
//      ids 272..287 V@Wo 128x128, the 16 z=0,m0=0 tiles (cost 1)
//      ids 288..767 V@Wo 128x64, remaining 240 tiles split in two (cost .5)
//    Round-robin placement -> per-CU load 2.0-2.5 units vs static-528's
//    3.0 makespan (measured 1.46x imbalance, R3/R6).
//  - R10: softmax traffic trim (load j<=i, store j<kend only).
//  - gemm_acc: double-buffered LDS, ONE barrier per K-step, BK=32.
//  - Swizzle: stage src chunk (l&3)^((l>>3)&3), read slot quad^((row>>1)&3).
//  - 5 dispatches: prep, QKV, mid (QK^T || V@Wo), softmax, PV->out

typedef _Float16 f16x8 __attribute__((ext_vector_type(8)));
typedef float f32x4 __attribute__((ext_vector_type(4)));

#define BK 32   // halves per LDS row (64 B)

__device__ __forceinline__ void gload_lds16(const void* g, void* l) {
  __builtin_amdgcn_global_load_lds(
      (const __attribute__((address_space(1))) void*)g,
      (__attribute__((address_space(3))) void*)l, 16, 0, 0);
}

// Accumulate C-tile (m0,n0) of A[*,sAr] @ BT[*,sBr]^T over k < kend.
// Ah/Bh are double buffers: 2 * TMp*BK / 2 * TNp*BK halves.
// LDS: [row][chunk] chunks of 8 halves (16B); logical chunk c of row r at
// physical slot c ^ ((r>>1)&3). Staging swizzles the global source side
// (global_load_lds LDS dest must stay lane-linear); ds_read mirrors it.
template<int TMp, int TNp>
__device__ __forceinline__ void gemm_acc(
    const _Float16* __restrict__ A, const _Float16* __restrict__ BT,
    _Float16* Ah, _Float16* Bh, int sAr, int sBr, int kend, int m0, int n0,
    f32x4 (&acc)[TMp / 32][TNp / 32])
{
  const int tid  = threadIdx.x;
  const int lane = tid & 63;
  const int wid  = tid >> 6;
  const int wm   = (wid >> 1) * (TMp / 2);
  const int wn   = (wid & 1) * (TNp / 2);
  const int l15  = lane & 15;
  const int quad = lane >> 4;
  constexpr int MT = TMp / 32;
  constexpr int NT = TNp / 32;
  constexpr int AI = TMp / 64;            // staging instrs per wave (16 rows)
  constexpr int BI = TNp / 64;
  const int r16 = lane >> 2;              // row within 16-row group
  const int swc = ((lane & 3) ^ ((lane >> 3) & 3)) * 8;  // swizzled src chunk
  const int arow = wid * (TMp / 4);
  const int brow = wid * (TNp / 4);

  auto stage = [&](int k0, int buf) {
    _Float16* Ad = Ah + buf * (TMp * BK);
    _Float16* Bd = Bh + buf * (TNp * BK);
    #pragma unroll
    for (int t = 0; t < AI; ++t)
      gload_lds16(A + (long long)(m0 + arow + t * 16 + r16) * sAr + k0 + swc,
                  Ad + (arow + t * 16) * BK);
    #pragma unroll
    for (int t = 0; t < BI; ++t)
      gload_lds16(BT + (long long)(n0 + brow + t * 16 + r16) * sBr + k0 + swc,
                  Bd + (brow + t * 16) * BK);
  };

  stage(0, 0);
  __syncthreads();                        // drain vmcnt(0) for step 0
  int cur = 0;
  for (int k0 = 0; k0 < kend; k0 += BK) {
    if (k0 + BK < kend) stage(k0 + BK, cur ^ 1);   // prefetch next step

    const int ch = (quad ^ ((l15 >> 1) & 3)) * 8;  // swizzled read slot
    const _Float16* ab = Ah + cur * (TMp * BK) + (wm + l15) * BK + ch;
    const _Float16* bb = Bh + cur * (TNp * BK) + (wn + l15) * BK + ch;
    f16x8 af[MT], bf[NT];
    #pragma unroll
    for (int t = 0; t < MT; ++t) af[t] = *(const f16x8*)(ab + t * 16 * BK);
    #pragma unroll
    for (int t = 0; t < NT; ++t) bf[t] = *(const f16x8*)(bb + t * 16 * BK);
    #pragma unroll
    for (int mt = 0; mt < MT; ++mt)
      #pragma unroll
      for (int nt = 0; nt < NT; ++nt)
        acc[mt][nt] = __builtin_amdgcn_mfma_f32_16x16x32_f16(
            af[mt], bf[nt], acc[mt][nt], 0, 0, 0);

    __syncthreads();   // one barrier/step: drains prefetch vmcnt + syncs reads
    cur ^= 1;
  }
}

// Epilogue. C/D layout: col = lane&15, row = quad*4 + reg (HW-verified).
template<int TMp, int TNp, bool RELU, bool HAS_BIAS, typename OT>
__device__ __forceinline__ void gemm_store(
    f32x4 (&acc)[TMp / 32][TNp / 32], const float* __restrict__ bias,
    OT* __restrict__ C, int Nout, float scale, int m0, int n0)
{
  const int tid  = threadIdx.x;
  const int lane = tid & 63;
  const int wid  = tid >> 6;
  const int wm   = (wid >> 1) * (TMp / 2);
  const int wn   = (wid & 1) * (TNp / 2);
  const int l15  = lane & 15;
  const int quad = lane >> 4;
  constexpr int MT = TMp / 32;
  constexpr int NT = TNp / 32;

  float bvals[NT];
  if (HAS_BIAS) {
    #pragma unroll
    for (int nt = 0; nt < NT; ++nt)
      bvals[nt] = bias[n0 + wn + nt * 16 + l15];
  }
  #pragma unroll
  for (int mt = 0; mt < MT; ++mt) {
    #pragma unroll
    for (int nt = 0; nt < NT; ++nt) {
      const int col = n0 + wn + nt * 16 + l15;
      #pragma unroll
      for (int r = 0; r < 4; ++r) {
        const int row = m0 + wm + mt * 16 + quad * 4 + r;
        float v = acc[mt][nt][r] * scale;
        if (HAS_BIAS) v += bvals[nt];
        if (RELU) v = fmaxf(v, 0.f);
        C[(long long)row * Nout + col] = (OT)v;
      }
    }
  }
}

// fused QKV: relu(x @ W{q,k,v} + b) -> f16; Wcat = [Wq^T;Wk^T;Wv^T;Wo^T]
__global__ __launch_bounds__(256) void qkv_kernel(
    const _Float16* __restrict__ xh, const _Float16* __restrict__ Wcat,
    const float* __restrict__ bq, const float* __restrict__ bk,
    const float* __restrict__ bv,
    _Float16* __restrict__ Qh, _Float16* __restrict__ Kh,
    _Float16* __restrict__ Vh, int D)
{
  __shared__ _Float16 Ah[2 * 128 * BK];
  __shared__ _Float16 Bh[2 * 128 * BK];
  const int m0  = blockIdx.y * 128;
  const int n0g = blockIdx.x * 128;       // 0..3071
  f32x4 acc[4][4];
  #pragma unroll
  for (int i = 0; i < 4; ++i)
    #pragma unroll
    for (int j = 0; j < 4; ++j) acc[i][j] = (f32x4){0.f, 0.f, 0.f, 0.f};

  gemm_acc<128, 128>(xh, Wcat, Ah, Bh, D, D, D, m0, n0g, acc);

  const int mat = n0g >> 10;              // D = 1024
  const int c0  = n0g & 1023;
  _Float16* C = (mat == 0) ? Qh : (mat == 1) ? Kh : Vh;
  const float* bias = (mat == 0) ? bq : (mat == 1) ? bk : bv;
  gemm_store<128, 128, true, true, _Float16>(acc, bias, C, D, 1.0f, m0, c0);
}

// mid: static mixed-granularity, 768 blocks (3/CU), heavy-first:
//   ids 0..271   : QK^T 128x128, packed triangular, 136/batch (cost 1)
//   ids 272..287 : V@Wo 128x128, the 16 tiles z=0,m0=0 (cost 1)
//   ids 288..767 : V@Wo 128x64, remaining 240 128^2 tiles split x2 (cost .5)
// Diagonal QK^T tiles compute a garbage upper half; softmax zeroes the
// region pv reads (j < kend) and pv never reads past kend.
__global__ __launch_bounds__(256) void mid_kernel(
    const _Float16* __restrict__ Qh, const _Float16* __restrict__ Kh,
    _Float16* __restrict__ E, const _Float16* __restrict__ WoT,
    const _Float16* __restrict__ Vh, _Float16* __restrict__ VWT,
    int S, int D)
{
  __shared__ _Float16 Ah[2 * 128 * BK];
  __shared__ _Float16 Bh[2 * 128 * BK];
  const int id = blockIdx.x;

  if (id < 272) {                          // QK^T, 136 tiles per batch
    const int z = (id >= 136);
    const int t = id - z * 136;
    int i = (int)((sqrtf(8.f * t + 1.f) - 1.f) * 0.5f);
    while ((i + 1) * (i + 2) / 2 <= t) ++i;
    while (i * (i + 1) / 2 > t) --i;
    const int j = t - i * (i + 1) / 2;     // 0..i
    const int m0 = i * 128;
    const int n0 = j * 128;
    const _Float16* A  = Qh + (long long)z * S * D;
    const _Float16* BT = Kh + (long long)z * S * D;
    _Float16* C = E + (long long)z * S * S;
    f32x4 acc[4][4];
    #pragma unroll
    for (int a = 0; a < 4; ++a)
      #pragma unroll
      for (int b = 0; b < 4; ++b) acc[a][b] = (f32x4){0.f, 0.f, 0.f, 0.f};
    gemm_acc<128, 128>(A, BT, Ah, Bh, D, D, D, m0, n0, acc);
    gemm_store<128, 128, false, false, _Float16>(acc, nullptr, C, S,
                                                 0.03125f, m0, n0);
  } else if (id < 288) {                   // V@Wo 128x128: z=0, m0=0 row
    const int v = id - 272;                // 0..15
    const int m0 = 0;
    const int n0 = v * 128;
    const _Float16* A  = WoT;
    const _Float16* BT = Vh;               // z = 0
    _Float16* C = VWT;
    f32x4 acc[4][4];
    #pragma unroll
    for (int a = 0; a < 4; ++a)
      #pragma unroll
      for (int b = 0; b < 4; ++b) acc[a][b] = (f32x4){0.f, 0.f, 0.f, 0.f};
    gemm_acc<128, 128>(A, BT, Ah, Bh, D, D, D, m0, n0, acc);
    gemm_store<128, 128, false, false, _Float16>(acc, nullptr, C, S,
                                                 1.0f, m0, n0);
  } else {                                 // V@Wo 128x64 halves of tiles 16..255
    const int w  = id - 288;               // 0..479
    const int v  = 16 + (w >> 1);          // 128^2 tile index 16..255
    const int hf = w & 1;
    const int z  = v >> 7;
    const int m0 = ((v >> 4) & 7) * 128;
    const int n0 = (v & 15) * 128 + hf * 64;
    const _Float16* A  = WoT;
    const _Float16* BT = Vh + (long long)z * S * D;
    _Float16* C = VWT + (long long)z * D * S;
    f32x4 acc[4][2];
    #pragma unroll
    for (int a = 0; a < 4; ++a)
      #pragma unroll
      for (int b = 0; b < 2; ++b) acc[a][b] = (f32x4){0.f, 0.f, 0.f, 0.f};
    gemm_acc<128, 64>(A, BT, Ah, Bh, D, D, D, m0, n0, acc);
    gemm_store<128, 64, false, false, _Float16>(acc, nullptr, C, S,
                                                1.0f, m0, n0);
  }
}

// out = relu(P @ VW + bo) -> fp32; kend = m0+64 (causal cap); heavy tiles first
__global__ __launch_bounds__(256) void pv_kernel(
    const _Float16* __restrict__ E, const _Float16* __restrict__ VWT,
    const float* __restrict__ bo, float* __restrict__ out, int S, int D)
{
  __shared__ _Float16 Ah[2 * 64 * BK];
  __shared__ _Float16 Bh[2 * 128 * BK];
  const int z  = blockIdx.z;
  const int m0 = ((int)gridDim.y - 1 - (int)blockIdx.y) * 64;
  const int n0 = blockIdx.x * 128;
  const _Float16* A  = E + (long long)z * S * S;
  const _Float16* BT = VWT + (long long)z * D * S;
  float* C = out + (long long)z * S * D;
  const int kend = m0 + 64;

  f32x4 acc[2][4];
  #pragma unroll
  for (int i = 0; i < 2; ++i)
    #pragma unroll
    for (int j = 0; j < 4; ++j) acc[i][j] = (f32x4){0.f, 0.f, 0.f, 0.f};

  gemm_acc<64, 128>(A, BT, Ah, Bh, S, S, kend, m0, n0, acc);
  gemm_store<64, 128, true, true, float>(acc, bo, C, D, 1.0f, m0, n0);
}

// prep: blocks 0..2047 = x fp32->f16 (8 elems/thread);
//       blocks 2048..3071 = W transpose+convert into Wcat (64x64 tiles, z=mat)
__global__ __launch_bounds__(256) void prep_kernel(
    const float* __restrict__ x, _Float16* __restrict__ xh,
    const float* __restrict__ W0, const float* __restrict__ W1,
    const float* __restrict__ W2, const float* __restrict__ W3,
    _Float16* __restrict__ Wcat, int D)
{
  const int id = blockIdx.x;
  const int tid = threadIdx.x;
  if (id < 2048) {
    const long long i = ((long long)id * 256 + tid) * 8;
    float4 a = *(const float4*)(x + i);
    float4 b = *(const float4*)(x + i + 4);
    f16x8 o = {(_Float16)a.x, (_Float16)a.y, (_Float16)a.z, (_Float16)a.w,
               (_Float16)b.x, (_Float16)b.y, (_Float16)b.z, (_Float16)b.w};
    *(f16x8*)(xh + i) = o;
    return;
  }
  __shared__ _Float16 t[64][72];
  const int u = id - 2048;
  const int z = u >> 8;
  const int v = u & 255;
  const float* W = (z == 0) ? W0 : (z == 1) ? W1 : (z == 2) ? W2 : W3;
  _Float16* dst = Wcat + (long long)z * D * D;
  const int k0 = (v >> 4) * 64, n0 = (v & 15) * 64;
  #pragma unroll
  for (int it = 0; it < 4; ++it) {
    int idx = tid + it * 256;
    int r = idx >> 4, c4 = (idx & 15) << 2;
    float4 w = *(const float4*)(W + (long long)(k0 + r) * D + n0 + c4);
    t[r][c4 + 0] = (_Float16)w.x; t[r][c4 + 1] = (_Float16)w.y;
    t[r][c4 + 2] = (_Float16)w.z; t[r][c4 + 3] = (_Float16)w.w;
  }
  __syncthreads();
  #pragma unroll
  for (int it = 0; it < 2; ++it) {
    int idx = tid + it * 256;
    int r = idx >> 3, c8 = (idx & 7) << 3;
    f16x8 o;
    #pragma unroll
    for (int j = 0; j < 8; ++j) o[j] = t[c8 + j][r];
    *(f16x8*)(dst + (long long)(n0 + r) * D + k0 + c8) = o;
  }
}

// in-place causal softmax, fp32 math, f16 IO; zeros for j > i.
// Load only j0 < n (rest contribute -inf/0 to the reductions);
// store only j0 < kend=(i&~63)+64 -- pv's K-loop never reads past kend,
// so raw mid garbage may remain at j >= kend. No early returns: every
// thread reaches both __syncthreads.
__global__ __launch_bounds__(256) void softmax_causal_h(
    _Float16* __restrict__ E, int S)
{
  const int i = blockIdx.x;
  _Float16* row = E + ((long long)blockIdx.y * S + i) * S;
  const int tid = threadIdx.x;
  const int n = i + 1;
  const int kend = (i & ~63) + 64;
  const int j0 = tid * 8;

  f16x8 hv;
  const bool has = (j0 < n);
  if (has) hv = *(const f16x8*)(row + j0);
  float vals[8];
  float m = -3.0e38f;
  #pragma unroll
  for (int t = 0; t < 8; ++t) {
    float v = (has && j0 + t < n) ? (float)hv[t] : -3.0e38f;
    vals[t] = v;
    m = fmaxf(m, v);
  }
  #pragma unroll
  for (int o = 32; o > 0; o >>= 1) m = fmaxf(m, __shfl_down(m, o, 64));

  __shared__ float rmax[4];
  __shared__ float rsum[4];
  const int wave = tid >> 6;
  if ((tid & 63) == 0) rmax[wave] = m;
  __syncthreads();
  m = fmaxf(fmaxf(rmax[0], rmax[1]), fmaxf(rmax[2], rmax[3]));

  float s = 0.f;
  #pragma unroll
  for (int t = 0; t < 8; ++t) {
    float e = (has && j0 + t < n) ? expf(vals[t] - m) : 0.f;
    vals[t] = e;
    s += e;
  }
  #pragma unroll
  for (int o = 32; o > 0; o >>= 1) s += __shfl_down(s, o, 64);
  if ((tid & 63) == 0) rsum[wave] = s;
  __syncthreads();
  s = rsum[0] + rsum[1] + rsum[2] + rsum[3];

  if (j0 < kend) {
    const float inv = 1.0f / s;
    f16x8 ov;
    #pragma unroll
    for (int t = 0; t < 8; ++t) ov[t] = (_Float16)(vals[t] * inv);
    *(f16x8*)(row + j0) = ov;
  }
}

extern "C" void kernel_launch(void* const* d_in, const int* in_sizes, int n_in,
                              void* d_out, int out_size, void* d_ws, size_t ws_size,
                              hipStream_t stream) {
  const float* x  = (const float*)d_in[0];
  const float* Wq = (const float*)d_in[1];
  const float* bq = (const float*)d_in[2];
  const float* Wk = (const float*)d_in[3];
  const float* bk = (const float*)d_in[4];
  const float* Wv = (const float*)d_in[5];
  const float* bv = (const float*)d_in[6];
  const float* Wo = (const float*)d_in[7];
  const float* bo = (const float*)d_in[8];
  float* out = (float*)d_out;

  const int Bn = 2, S = 2048, D = 1024;
  const int M = Bn * S;                       // 4096
  const size_t MD = (size_t)M * D;            // 4M elems
  const size_t DD = (size_t)D * D;            // 1M
  const size_t SS = (size_t)Bn * S * S;       // 8M

  _Float16* ws   = (_Float16*)d_ws;
  _Float16* xh   = ws;                 // MD
  _Float16* Wcat = xh + MD;            // 4*DD
  _Float16* Qh   = Wcat + 4 * DD;      // MD
  _Float16* Kh   = Qh + MD;            // MD
  _Float16* Vh   = Kh + MD;            // MD
  _Float16* VWT  = Vh + MD;            // MD  ((V@Wo)^T, [D,S] per batch)
  _Float16* E    = VWT + MD;           // SS

  dim3 blk(256);

  prep_kernel<<<dim3(3072), blk, 0, stream>>>(x, xh, Wq, Wk, Wv, Wo, Wcat, D);

  qkv_kernel<<<dim3(3 * D / 128, M / 128), blk, 0, stream>>>(
      xh, Wcat, bq, bk, bv, Qh, Kh, Vh, D);

  mid_kernel<<<dim3(768), blk, 0, stream>>>(
      Qh, Kh, E, Wcat + 3 * DD, Vh, VWT, S, D);

  softmax_causal_h<<<dim3(S, Bn), blk, 0, stream>>>(E, S);

  pv_kernel<<<dim3(D / 128, S / 64, Bn), blk, 0, stream>>>(
      E, VWT, bo, out, S, D);
}

// Round 12
// 193.934 us; speedup vs baseline: 1.1029x; 1.0185x over previous
//
#include <hip/hip_runtime.h>
#include <math.h>

// fp16-MFMA fused MHA-like layer (fp32 accumulate), round 14:
//  - R14: pv static load-balance. Round-robin pairs CU c with blocks
//    (z=0,strip y) + (z=1,strip y). Old code reversed strips for BOTH z
//    -> CU pairs had equal kend (2048+2048 worst, 64+64 best): ~2x
//    makespan. Now z=0 descending, z=1 ascending -> per-CU kend sum
//    = 2112 constant. Pure index change, no structural risk.
//  - mid: reverted to R10-verified static-528 (R13 static-mixed was
//    neutral; mid-balance direction closed after 5 null rounds).
//  - R10: softmax traffic trim (load j<=i, store j<kend only).
//  - gemm_acc: double-buffered LDS, ONE barrier per K-step, BK=32.
//  - Swizzle: stage src chunk (l&3)^((l>>3)&3), read slot quad^((row>>1)&3).
//  - 5 dispatches: prep, QKV, mid (QK^T || V@Wo), softmax, PV->out

typedef _Float16 f16x8 __attribute__((ext_vector_type(8)));
typedef float f32x4 __attribute__((ext_vector_type(4)));

#define BK 32   // halves per LDS row (64 B)

__device__ __forceinline__ void gload_lds16(const void* g, void* l) {
  __builtin_amdgcn_global_load_lds(
      (const __attribute__((address_space(1))) void*)g,
      (__attribute__((address_space(3))) void*)l, 16, 0, 0);
}

// Accumulate C-tile (m0,n0) of A[*,sAr] @ BT[*,sBr]^T over k < kend.
// Ah/Bh are double buffers: 2 * TMp*BK / 2 * TNp*BK halves.
// LDS: [row][chunk] chunks of 8 halves (16B); logical chunk c of row r at
// physical slot c ^ ((r>>1)&3). Staging swizzles the global source side
// (global_load_lds LDS dest must stay lane-linear); ds_read mirrors it.
template<int TMp, int TNp>
__device__ __forceinline__ void gemm_acc(
    const _Float16* __restrict__ A, const _Float16* __restrict__ BT,
    _Float16* Ah, _Float16* Bh, int sAr, int sBr, int kend, int m0, int n0,
    f32x4 (&acc)[TMp / 32][TNp / 32])
{
  const int tid  = threadIdx.x;
  const int lane = tid & 63;
  const int wid  = tid >> 6;
  const int wm   = (wid >> 1) * (TMp / 2);
  const int wn   = (wid & 1) * (TNp / 2);
  const int l15  = lane & 15;
  const int quad = lane >> 4;
  constexpr int MT = TMp / 32;
  constexpr int NT = TNp / 32;
  constexpr int AI = TMp / 64;            // staging instrs per wave (16 rows)
  constexpr int BI = TNp / 64;
  const int r16 = lane >> 2;              // row within 16-row group
  const int swc = ((lane & 3) ^ ((lane >> 3) & 3)) * 8;  // swizzled src chunk
  const int arow = wid * (TMp / 4);
  const int brow = wid * (TNp / 4);

  auto stage = [&](int k0, int buf) {
    _Float16* Ad = Ah + buf * (TMp * BK);
    _Float16* Bd = Bh + buf * (TNp * BK);
    #pragma unroll
    for (int t = 0; t < AI; ++t)
      gload_lds16(A + (long long)(m0 + arow + t * 16 + r16) * sAr + k0 + swc,
                  Ad + (arow + t * 16) * BK);
    #pragma unroll
    for (int t = 0; t < BI; ++t)
      gload_lds16(BT + (long long)(n0 + brow + t * 16 + r16) * sBr + k0 + swc,
                  Bd + (brow + t * 16) * BK);
  };

  stage(0, 0);
  __syncthreads();                        // drain vmcnt(0) for step 0
  int cur = 0;
  for (int k0 = 0; k0 < kend; k0 += BK) {
    if (k0 + BK < kend) stage(k0 + BK, cur ^ 1);   // prefetch next step

    const int ch = (quad ^ ((l15 >> 1) & 3)) * 8;  // swizzled read slot
    const _Float16* ab = Ah + cur * (TMp * BK) + (wm + l15) * BK + ch;
    const _Float16* bb = Bh + cur * (TNp * BK) + (wn + l15) * BK + ch;
    f16x8 af[MT], bf[NT];
    #pragma unroll
    for (int t = 0; t < MT; ++t) af[t] = *(const f16x8*)(ab + t * 16 * BK);
    #pragma unroll
    for (int t = 0; t < NT; ++t) bf[t] = *(const f16x8*)(bb + t * 16 * BK);
    #pragma unroll
    for (int mt = 0; mt < MT; ++mt)
      #pragma unroll
      for (int nt = 0; nt < NT; ++nt)
        acc[mt][nt] = __builtin_amdgcn_mfma_f32_16x16x32_f16(
            af[mt], bf[nt], acc[mt][nt], 0, 0, 0);

    __syncthreads();   // one barrier/step: drains prefetch vmcnt + syncs reads
    cur ^= 1;
  }
}

// Epilogue. C/D layout: col = lane&15, row = quad*4 + reg (HW-verified).
template<int TMp, int TNp, bool RELU, bool HAS_BIAS, typename OT>
__device__ __forceinline__ void gemm_store(
    f32x4 (&acc)[TMp / 32][TNp / 32], const float* __restrict__ bias,
    OT* __restrict__ C, int Nout, float scale, int m0, int n0)
{
  const int tid  = threadIdx.x;
  const int lane = tid & 63;
  const int wid  = tid >> 6;
  const int wm   = (wid >> 1) * (TMp / 2);
  const int wn   = (wid & 1) * (TNp / 2);
  const int l15  = lane & 15;
  const int quad = lane >> 4;
  constexpr int MT = TMp / 32;
  constexpr int NT = TNp / 32;

  float bvals[NT];
  if (HAS_BIAS) {
    #pragma unroll
    for (int nt = 0; nt < NT; ++nt)
      bvals[nt] = bias[n0 + wn + nt * 16 + l15];
  }
  #pragma unroll
  for (int mt = 0; mt < MT; ++mt) {
    #pragma unroll
    for (int nt = 0; nt < NT; ++nt) {
      const int col = n0 + wn + nt * 16 + l15;
      #pragma unroll
      for (int r = 0; r < 4; ++r) {
        const int row = m0 + wm + mt * 16 + quad * 4 + r;
        float v = acc[mt][nt][r] * scale;
        if (HAS_BIAS) v += bvals[nt];
        if (RELU) v = fmaxf(v, 0.f);
        C[(long long)row * Nout + col] = (OT)v;
      }
    }
  }
}

// fused QKV: relu(x @ W{q,k,v} + b) -> f16; Wcat = [Wq^T;Wk^T;Wv^T;Wo^T]
__global__ __launch_bounds__(256) void qkv_kernel(
    const _Float16* __restrict__ xh, const _Float16* __restrict__ Wcat,
    const float* __restrict__ bq, const float* __restrict__ bk,
    const float* __restrict__ bv,
    _Float16* __restrict__ Qh, _Float16* __restrict__ Kh,
    _Float16* __restrict__ Vh, int D)
{
  __shared__ _Float16 Ah[2 * 128 * BK];
  __shared__ _Float16 Bh[2 * 128 * BK];
  const int m0  = blockIdx.y * 128;
  const int n0g = blockIdx.x * 128;       // 0..3071
  f32x4 acc[4][4];
  #pragma unroll
  for (int i = 0; i < 4; ++i)
    #pragma unroll
    for (int j = 0; j < 4; ++j) acc[i][j] = (f32x4){0.f, 0.f, 0.f, 0.f};

  gemm_acc<128, 128>(xh, Wcat, Ah, Bh, D, D, D, m0, n0g, acc);

  const int mat = n0g >> 10;              // D = 1024
  const int c0  = n0g & 1023;
  _Float16* C = (mat == 0) ? Qh : (mat == 1) ? Kh : Vh;
  const float* bias = (mat == 0) ? bq : (mat == 1) ? bk : bv;
  gemm_store<128, 128, true, true, _Float16>(acc, bias, C, D, 1.0f, m0, c0);
}

// mid: blocks 0..271 -> E = QK^T/32 (packed triangular, 128x128 tiles);
//      blocks 272..527 -> VWT = (V@Wo)^T (A = Wo^T, BT = V), 128x128 tiles.
// Diagonal QK^T tiles compute a garbage upper half; softmax zeroes the
// region pv reads (j < kend) and pv never reads past kend.
__global__ __launch_bounds__(256) void mid_kernel(
    const _Float16* __restrict__ Qh, const _Float16* __restrict__ Kh,
    _Float16* __restrict__ E, const _Float16* __restrict__ WoT,
    const _Float16* __restrict__ Vh, _Float16* __restrict__ VWT,
    int S, int D)
{
  __shared__ _Float16 Ah[2 * 128 * BK];
  __shared__ _Float16 Bh[2 * 128 * BK];
  const _Float16 *A, *BT;
  _Float16* C;
  int m0, n0;
  float scale;
  const int id = blockIdx.x;
  if (id < 272) {                          // QK^T, 136 tiles per batch
    const int z = (id >= 136);
    const int t = id - z * 136;
    int i = (int)((sqrtf(8.f * t + 1.f) - 1.f) * 0.5f);
    while ((i + 1) * (i + 2) / 2 <= t) ++i;
    while (i * (i + 1) / 2 > t) --i;
    const int j = t - i * (i + 1) / 2;     // 0..i
    m0 = i * 128;
    n0 = j * 128;
    A  = Qh + (long long)z * S * D;
    BT = Kh + (long long)z * S * D;
    C  = E + (long long)z * S * S;
    scale = 0.03125f;
  } else {                                 // V @ Wo, 128 tiles per batch
    const int t = id - 272;
    const int z = t >> 7;
    const int u = t & 127;
    m0 = (u >> 4) * 128;                   // D rows of Wo^T
    n0 = (u & 15) * 128;                   // S cols (V rows)
    A  = WoT;
    BT = Vh + (long long)z * S * D;
    C  = VWT + (long long)z * D * S;
    scale = 1.0f;
  }
  f32x4 acc[4][4];
  #pragma unroll
  for (int i = 0; i < 4; ++i)
    #pragma unroll
    for (int j = 0; j < 4; ++j) acc[i][j] = (f32x4){0.f, 0.f, 0.f, 0.f};

  gemm_acc<128, 128>(A, BT, Ah, Bh, D, D, D, m0, n0, acc);
  gemm_store<128, 128, false, false, _Float16>(acc, nullptr, C, S, scale,
                                               m0, n0);
}

// out = relu(P @ VW + bo) -> fp32; kend = m0+64 (causal cap).
// R14 balance: round-robin pairs CU c with blocks (z=0,y) and (z=1,y);
// z=0 strips descending, z=1 ascending -> per-CU kend sum = 2112 const.
__global__ __launch_bounds__(256) void pv_kernel(
    const _Float16* __restrict__ E, const _Float16* __restrict__ VWT,
    const float* __restrict__ bo, float* __restrict__ out, int S, int D)
{
  __shared__ _Float16 Ah[2 * 64 * BK];
  __shared__ _Float16 Bh[2 * 128 * BK];
  const int z  = blockIdx.z;
  const int gy = (int)gridDim.y;
  const int m0 = ((z == 0) ? (gy - 1 - (int)blockIdx.y) : (int)blockIdx.y) * 64;
  const int n0 = blockIdx.x * 128;
  const _Float16* A  = E + (long long)z * S * S;
  const _Float16* BT = VWT + (long long)z * D * S;
  float* C = out + (long long)z * S * D;
  const int kend = m0 + 64;

  f32x4 acc[2][4];
  #pragma unroll
  for (int i = 0; i < 2; ++i)
    #pragma unroll
    for (int j = 0; j < 4; ++j) acc[i][j] = (f32x4){0.f, 0.f, 0.f, 0.f};

  gemm_acc<64, 128>(A, BT, Ah, Bh, S, S, kend, m0, n0, acc);
  gemm_store<64, 128, true, true, float>(acc, bo, C, D, 1.0f, m0, n0);
}

// prep: blocks 0..2047 = x fp32->f16 (8 elems/thread);
//       blocks 2048..3071 = W transpose+convert into Wcat (64x64 tiles, z=mat)
__global__ __launch_bounds__(256) void prep_kernel(
    const float* __restrict__ x, _Float16* __restrict__ xh,
    const float* __restrict__ W0, const float* __restrict__ W1,
    const float* __restrict__ W2, const float* __restrict__ W3,
    _Float16* __restrict__ Wcat, int D)
{
  const int id = blockIdx.x;
  const int tid = threadIdx.x;
  if (id < 2048) {
    const long long i = ((long long)id * 256 + tid) * 8;
    float4 a = *(const float4*)(x + i);
    float4 b = *(const float4*)(x + i + 4);
    f16x8 o = {(_Float16)a.x, (_Float16)a.y, (_Float16)a.z, (_Float16)a.w,
               (_Float16)b.x, (_Float16)b.y, (_Float16)b.z, (_Float16)b.w};
    *(f16x8*)(xh + i) = o;
    return;
  }
  __shared__ _Float16 t[64][72];
  const int u = id - 2048;
  const int z = u >> 8;
  const int v = u & 255;
  const float* W = (z == 0) ? W0 : (z == 1) ? W1 : (z == 2) ? W2 : W3;
  _Float16* dst = Wcat + (long long)z * D * D;
  const int k0 = (v >> 4) * 64, n0 = (v & 15) * 64;
  #pragma unroll
  for (int it = 0; it < 4; ++it) {
    int idx = tid + it * 256;
    int r = idx >> 4, c4 = (idx & 15) << 2;
    float4 w = *(const float4*)(W + (long long)(k0 + r) * D + n0 + c4);
    t[r][c4 + 0] = (_Float16)w.x; t[r][c4 + 1] = (_Float16)w.y;
    t[r][c4 + 2] = (_Float16)w.z; t[r][c4 + 3] = (_Float16)w.w;
  }
  __syncthreads();
  #pragma unroll
  for (int it = 0; it < 2; ++it) {
    int idx = tid + it * 256;
    int r = idx >> 3, c8 = (idx & 7) << 3;
    f16x8 o;
    #pragma unroll
    for (int j = 0; j < 8; ++j) o[j] = t[c8 + j][r];
    *(f16x8*)(dst + (long long)(n0 + r) * D + k0 + c8) = o;
  }
}

// in-place causal softmax, fp32 math, f16 IO; zeros for j > i.
// Load only j0 < n (rest contribute -inf/0 to the reductions);
// store only j0 < kend=(i&~63)+64 -- pv's K-loop never reads past kend,
// so raw mid garbage may remain at j >= kend. No early returns: every
// thread reaches both __syncthreads.
__global__ __launch_bounds__(256) void softmax_causal_h(
    _Float16* __restrict__ E, int S)
{
  const int i = blockIdx.x;
  _Float16* row = E + ((long long)blockIdx.y * S + i) * S;
  const int tid = threadIdx.x;
  const int n = i + 1;
  const int kend = (i & ~63) + 64;
  const int j0 = tid * 8;

  f16x8 hv;
  const bool has = (j0 < n);
  if (has) hv = *(const f16x8*)(row + j0);
  float vals[8];
  float m = -3.0e38f;
  #pragma unroll
  for (int t = 0; t < 8; ++t) {
    float v = (has && j0 + t < n) ? (float)hv[t] : -3.0e38f;
    vals[t] = v;
    m = fmaxf(m, v);
  }
  #pragma unroll
  for (int o = 32; o > 0; o >>= 1) m = fmaxf(m, __shfl_down(m, o, 64));

  __shared__ float rmax[4];
  __shared__ float rsum[4];
  const int wave = tid >> 6;
  if ((tid & 63) == 0) rmax[wave] = m;
  __syncthreads();
  m = fmaxf(fmaxf(rmax[0], rmax[1]), fmaxf(rmax[2], rmax[3]));

  float s = 0.f;
  #pragma unroll
  for (int t = 0; t < 8; ++t) {
    float e = (has && j0 + t < n) ? expf(vals[t] - m) : 0.f;
    vals[t] = e;
    s += e;
  }
  #pragma unroll
  for (int o = 32; o > 0; o >>= 1) s += __shfl_down(s, o, 64);
  if ((tid & 63) == 0) rsum[wave] = s;
  __syncthreads();
  s = rsum[0] + rsum[1] + rsum[2] + rsum[3];

  if (j0 < kend) {
    const float inv = 1.0f / s;
    f16x8 ov;
    #pragma unroll
    for (int t = 0; t < 8; ++t) ov[t] = (_Float16)(vals[t] * inv);
    *(f16x8*)(row + j0) = ov;
  }
}

extern "C" void kernel_launch(void* const* d_in, const int* in_sizes, int n_in,
                              void* d_out, int out_size, void* d_ws, size_t ws_size,
                              hipStream_t stream) {
  const float* x  = (const float*)d_in[0];
  const float* Wq = (const float*)d_in[1];
  const float* bq = (const float*)d_in[2];
  const float* Wk = (const float*)d_in[3];
  const float* bk = (const float*)d_in[4];
  const float* Wv = (const float*)d_in[5];
  const float* bv = (const float*)d_in[6];
  const float* Wo = (const float*)d_in[7];
  const float* bo = (const float*)d_in[8];
  float* out = (float*)d_out;

  const int Bn = 2, S = 2048, D = 1024;
  const int M = Bn * S;                       // 4096
  const size_t MD = (size_t)M * D;            // 4M elems
  const size_t DD = (size_t)D * D;            // 1M
  const size_t SS = (size_t)Bn * S * S;       // 8M

  _Float16* ws   = (_Float16*)d_ws;
  _Float16* xh   = ws;                 // MD
  _Float16* Wcat = xh + MD;            // 4*DD
  _Float16* Qh   = Wcat + 4 * DD;      // MD
  _Float16* Kh   = Qh + MD;            // MD
  _Float16* Vh   = Kh + MD;            // MD
  _Float16* VWT  = Vh + MD;            // MD  ((V@Wo)^T, [D,S] per batch)
  _Float16* E    = VWT + MD;           // SS

  dim3 blk(256);

  prep_kernel<<<dim3(3072), blk, 0, stream>>>(x, xh, Wq, Wk, Wv, Wo, Wcat, D);

  qkv_kernel<<<dim3(3 * D / 128, M / 128), blk, 0, stream>>>(
      xh, Wcat, bq, bk, bv, Qh, Kh, Vh, D);

  mid_kernel<<<dim3(528), blk, 0, stream>>>(
      Qh, Kh, E, Wcat + 3 * DD, Vh, VWT, S, D);

  softmax_causal_h<<<dim3(S, Bn), blk, 0, stream>>>(E, S);

  pv_kernel<<<dim3(D / 128, S / 64, Bn), blk, 0, stream>>>(
      E, VWT, bo, out, S, D);
}